// Round 8
// baseline (271.533 us; speedup 1.0000x reference)
//
#include <hip/hip_runtime.h>
#include <stdint.h>

#define NB   2
#define SS   2048
#define HIDN 1024
#define NHEAD 16
#define DKK  64

typedef __attribute__((ext_vector_type(8))) short bf16x8;
typedef __attribute__((ext_vector_type(4))) float f32x4;

__device__ __forceinline__ uint16_t f2bf(float f) {
    uint32_t u = __float_as_uint(f);
    u += 0x7FFF + ((u >> 16) & 1);
    return (uint16_t)(u >> 16);
}
__device__ __forceinline__ uint32_t pk2(float f0, float f1) {
    uint32_t u0 = __float_as_uint(f0);
    uint32_t u1 = __float_as_uint(f1);
    u0 += 0x7FFF + ((u0 >> 16) & 1);
    u1 += 0x7FFF + ((u1 >> 16) & 1);
    return (u0 >> 16) | (u1 & 0xFFFF0000u);
}
__device__ __forceinline__ uint4 pack8(const float* __restrict__ s, float sc) {
    float4 a = *(const float4*)s;
    float4 b = *(const float4*)(s + 4);
    uint4 r;
    r.x = pk2(sc * a.x, sc * a.y);
    r.y = pk2(sc * a.z, sc * a.w);
    r.z = pk2(sc * b.x, sc * b.y);
    r.w = pk2(sc * b.z, sc * b.w);
    return r;
}
// async global->LDS, 16B/lane; LDS dest = wave-uniform base + lane*16
__device__ __forceinline__ void gl_lds16(const uint16_t* g, uint16_t* l) {
    __builtin_amdgcn_global_load_lds((const __attribute__((address_space(1))) void*)g,
                                     (__attribute__((address_space(3))) void*)l,
                                     16, 0, 0);
}

// ---- fused conversion dispatch (HBM-bound) ----
__global__ __launch_bounds__(256, 4)
void cvt_all(const float* __restrict__ q, const float* __restrict__ k,
             const float* __restrict__ v, const float* __restrict__ bias,
             const float* __restrict__ w0, const float* __restrict__ w1,
             const float* __restrict__ w2, const float* __restrict__ w3,
             uint16_t* __restrict__ q16, uint16_t* __restrict__ k16,
             uint16_t* __restrict__ v16, uint16_t* __restrict__ w16o)
{
    int i = blockIdx.x * 256 + threadIdx.x;            // 0..1048575
    if (i < 524288) {                                  // q/k/v: 4M elems each
        size_t e = (size_t)i * 8;
        float sc = 1.0f + bias[i >> 7];
        *(uint4*)(q16 + e) = pack8(q + e, 1.0f);
        *(uint4*)(k16 + e) = pack8(k + e, sc);
        *(uint4*)(v16 + e) = pack8(v + e, sc);
    } else {
        int j = i - 524288;
        const float* src = (j < 131072) ? w0 : (j < 262144) ? w1
                         : (j < 393216) ? w2 : w3;
        size_t e = (size_t)(j & 131071) * 8;
        *(uint4*)(w16o + (size_t)(j >> 17) * 1048576 + e) = pack8(src + e, 1.0f);
    }
}

// ================= GEMM mainloop (m97 shape: 128x128 tile, BK=32) ============
// SM[buf] = [ As 128x32 | Bs 128x32 ] (stride-32 rows, no pad; bank-balanced).
// Double-buffered gl_lds, one barrier per iter; prefetch issued right after the
// barrier so the compiler's vmcnt(0)-before-next-barrier drains across compute.
__device__ __forceinline__ void gemm_core(const uint16_t* __restrict__ A,
                                          const uint16_t* __restrict__ W,
                                          uint16_t (*__restrict__ SM)[8192],
                                          int m0, int n0,
                                          f32x4 acc[4][4])
{
    const int t    = threadIdx.x;
    const int w    = t >> 6;
    const int lane = t & 63;
    const int q    = lane >> 4;
    const int lr   = lane & 15;
    const int wr   = (w >> 1) * 64;
    const int wc   = (w & 1) * 64;
    const int rsub = lane >> 2;                        // staging row-in-16
    const int cg   = (lane & 3) * 8;                   // staging col

    // preload k-tile 0 into buffer 0
#pragma unroll
    for (int p = 0; p < 2; ++p) {
        int rb = p * 64 + w * 16;
        gl_lds16(A + (size_t)(m0 + rb + rsub) * HIDN + cg, &SM[0][rb * 32]);
        gl_lds16(W + (size_t)(n0 + rb + rsub) * HIDN + cg, &SM[0][4096 + rb * 32]);
    }

    for (int it = 0; it < 32; ++it) {
        uint16_t* cur = SM[it & 1];
        uint16_t* nxt = SM[(it & 1) ^ 1];
        __syncthreads();
        if (it + 1 < 32) {
            int k0 = (it + 1) * 32;
#pragma unroll
            for (int p = 0; p < 2; ++p) {
                int rb = p * 64 + w * 16;
                gl_lds16(A + (size_t)(m0 + rb + rsub) * HIDN + k0 + cg,
                         &nxt[rb * 32]);
                gl_lds16(W + (size_t)(n0 + rb + rsub) * HIDN + k0 + cg,
                         &nxt[4096 + rb * 32]);
            }
        }
        bf16x8 af[4], bf[4];
#pragma unroll
        for (int i = 0; i < 4; ++i)
            af[i] = *(const bf16x8*)&cur[(wr + i * 16 + lr) * 32 + q * 8];
#pragma unroll
        for (int j = 0; j < 4; ++j)
            bf[j] = *(const bf16x8*)&cur[4096 + (wc + j * 16 + lr) * 32 + q * 8];
#pragma unroll
        for (int i = 0; i < 4; ++i)
#pragma unroll
            for (int j = 0; j < 4; ++j)
                acc[i][j] = __builtin_amdgcn_mfma_f32_16x16x32_bf16(
                    af[i], bf[j], acc[i][j], 0, 0, 0);
    }
}

// fused Q/K/V projections: grid (8, 32, 3)
__global__ __launch_bounds__(256, 3)
void gemm_qkv(const uint16_t* __restrict__ Qin, const uint16_t* __restrict__ Kin,
              const uint16_t* __restrict__ Vin, const uint16_t* __restrict__ W16,
              const float* __restrict__ bq, const float* __restrict__ bk,
              const float* __restrict__ bv,
              uint16_t* __restrict__ Qb, uint16_t* __restrict__ Kb,
              uint16_t* __restrict__ Vtb)
{
    __shared__ __align__(16) uint16_t SM[2][8192];

    const int z = blockIdx.z;
    const uint16_t* A    = (z == 0) ? Qin : (z == 1) ? Kin : Vin;
    const uint16_t* W    = W16 + (size_t)z * 1048576;
    const float*    bias = (z == 0) ? bq : (z == 1) ? bk : bv;
    const float     osc  = (z == 0) ? 0.125f : 1.0f;   // fold 1/sqrt(64) into Q

    const int t    = threadIdx.x;
    const int w    = t >> 6;
    const int lane = t & 63;
    const int q    = lane >> 4;
    const int lr   = lane & 15;
    const int wr   = (w >> 1) * 64;
    const int wc   = (w & 1) * 64;
    const int m0   = blockIdx.y * 128;
    const int n0   = blockIdx.x * 128;

    f32x4 acc[4][4] = {};
    gemm_core(A, W, SM, m0, n0, acc);

    if (z < 2) {
        // out bf16 [b][h][s][d]; C/D: col=lane&15, row=(lane>>4)*4+r
        uint16_t* o = (z == 0) ? Qb : Kb;
#pragma unroll
        for (int i = 0; i < 4; ++i)
#pragma unroll
            for (int j = 0; j < 4; ++j) {
                int gn = n0 + wc + j * 16 + lr;
                float bvx = bias[gn];
#pragma unroll
                for (int r = 0; r < 4; ++r) {
                    int row = m0 + wr + i * 16 + q * 4 + r;
                    int b = row >> 11, s = row & 2047;
                    size_t dst = (size_t)b * (NHEAD * SS * DKK)
                               + (size_t)(gn >> 6) * (SS * DKK)
                               + (size_t)s * DKK + (gn & 63);
                    o[dst] = f2bf((acc[i][j][r] + bvx) * osc);
                }
            }
    } else {
        // V^T in two 64-col halves via Tr (carved from SM staging buffers)
        uint16_t* Tr = &SM[0][0];                      // 64 x 136 = 17.4 KB
        int bb = m0 >> 11, hb = n0 >> 6;
#pragma unroll
        for (int dh = 0; dh < 2; ++dh) {
            __syncthreads();
            if ((w & 1) == dh) {
#pragma unroll
                for (int j = 0; j < 4; ++j) {
                    int dl = j * 16 + lr;              // local d 0..63
                    float bvx = bias[n0 + dh * 64 + dl];
#pragma unroll
                    for (int i = 0; i < 4; ++i)
#pragma unroll
                        for (int r = 0; r < 4; ++r)
                            Tr[dl * 136 + wr + i * 16 + q * 4 + r] =
                                f2bf(acc[i][j][r] + bvx);
                }
            }
            __syncthreads();
#pragma unroll
            for (int p = 0; p < 4; ++p) {
                int idx = p * 256 + t;
                int d   = idx >> 4;
                int sc8 = (idx & 15) * 8;
                size_t dst = ((size_t)(bb * NHEAD + hb + dh) * DKK + d) * SS
                           + (m0 & 2047) + sc8;
                *(uint4*)&Vtb[dst] = *(const uint4*)&Tr[d * 136 + sc8];
            }
        }
    }
}

// final projection: A bf16 (Xb), out fp32 d_out. grid (8, 32)
__global__ __launch_bounds__(256, 3)
void gemm_out(const uint16_t* __restrict__ Xb, const uint16_t* __restrict__ W,
              const float* __restrict__ bias, float* __restrict__ out)
{
    __shared__ __align__(16) uint16_t SM[2][8192];

    const int t    = threadIdx.x;
    const int w    = t >> 6;
    const int lane = t & 63;
    const int q    = lane >> 4;
    const int lr   = lane & 15;
    const int wr   = (w >> 1) * 64;
    const int wc   = (w & 1) * 64;
    const int m0   = blockIdx.y * 128;
    const int n0   = blockIdx.x * 128;

    f32x4 acc[4][4] = {};
    gemm_core(Xb, W, SM, m0, n0, acc);

#pragma unroll
    for (int i = 0; i < 4; ++i)
#pragma unroll
        for (int j = 0; j < 4; ++j) {
            int gn = n0 + wc + j * 16 + lr;
            float bvx = bias[gn];
#pragma unroll
            for (int r = 0; r < 4; ++r) {
                int row = m0 + wr + i * 16 + q * 4 + r;
                out[(size_t)row * HIDN + gn] = acc[i][j][r] + bvx;
            }
        }
}

// ---- flash attention, S^T form, 4 waves x 32 q-rows ----
// Per lane: 2 q-rows (mi blocks), 16 keys each. kf/vf ingest amortized over 2x
// q-rows vs round 7. Q pre-scaled by 1/8. P LDS round-trip is wave-private.
__global__ __launch_bounds__(256, 3)
void flash_attn(const uint16_t* __restrict__ Qg, const uint16_t* __restrict__ Kg,
                const uint16_t* __restrict__ Vtg, const int* __restrict__ mask,
                uint16_t* __restrict__ X)
{
    __shared__ __align__(16) uint16_t QP[128 * 72];   // Q, then per-wave P rows
    __shared__ __align__(16) uint16_t Ks[64 * 72];
    __shared__ __align__(16) uint16_t Vs[64 * 72];    // V^T tile [d][key]
    __shared__ __align__(16) float Amf[SS];           // additive mask

    const int t    = threadIdx.x;
    const int w    = t >> 6;                           // 0..3
    const int lane = t & 63;
    const int q    = lane >> 4;
    const int lr   = lane & 15;
    const int bh   = blockIdx.y;
    const int b    = bh >> 4;
    const int h    = bh & 15;
    const int q0   = blockIdx.x * 128;
    const size_t head = (size_t)bh * SS * DKK;

#pragma unroll
    for (int p = 0; p < 4; ++p) {
        int idx = p * 256 + t;
        int row = idx >> 3;
        int col = (idx & 7) * 8;
        *(uint4*)&QP[row * 72 + col] =
            *(const uint4*)(Qg + head + (size_t)(q0 + row) * DKK + col);
    }
    {
        const int4* mp = (const int4*)(mask + b * SS);
#pragma unroll
        for (int p = 0; p < 2; ++p) {
            int4 m4 = mp[p * 256 + t];
            float4 f;
            f.x = m4.x ? 0.0f : -10000.0f;
            f.y = m4.y ? 0.0f : -10000.0f;
            f.z = m4.z ? 0.0f : -10000.0f;
            f.w = m4.w ? 0.0f : -10000.0f;
            ((float4*)Amf)[p * 256 + t] = f;
        }
    }
    __syncthreads();

    // Q as B-operand, two column blocks (mi)
    bf16x8 qf[2][2];
#pragma unroll
    for (int mi = 0; mi < 2; ++mi)
#pragma unroll
        for (int s = 0; s < 2; ++s)
            qf[mi][s] = *(const bf16x8*)&QP[(w * 32 + mi * 16 + lr) * 72 +
                                            s * 32 + q * 8];

    float mst[2] = {-1e30f, -1e30f}, lst[2] = {0.0f, 0.0f};
    f32x4 oacc[2][4] = {};

    for (int kv0 = 0; kv0 < SS; kv0 += 64) {
#pragma unroll
        for (int p = 0; p < 2; ++p) {
            int idx = p * 256 + t;
            int row = idx >> 3;
            int col = (idx & 7) * 8;
            *(uint4*)&Ks[row * 72 + col] =
                *(const uint4*)(Kg + head + (size_t)(kv0 + row) * DKK + col);
            *(uint4*)&Vs[row * 72 + col] =
                *(const uint4*)(Vtg + head + (size_t)row * SS + kv0 + col);
        }
        __syncthreads();

        // S^T[key][q] = K · Q^T
        f32x4 st[2][4];
#pragma unroll
        for (int ni = 0; ni < 4; ++ni) {
            bf16x8 kf0 = *(const bf16x8*)&Ks[(ni * 16 + lr) * 72 + 0  + q * 8];
            bf16x8 kf1 = *(const bf16x8*)&Ks[(ni * 16 + lr) * 72 + 32 + q * 8];
#pragma unroll
            for (int mi = 0; mi < 2; ++mi) {
                f32x4 z = {0.0f, 0.0f, 0.0f, 0.0f};
                z = __builtin_amdgcn_mfma_f32_16x16x32_bf16(kf0, qf[mi][0], z, 0, 0, 0);
                z = __builtin_amdgcn_mfma_f32_16x16x32_bf16(kf1, qf[mi][1], z, 0, 0, 0);
                st[mi][ni] = z;
            }
        }

        float rmax[2] = {-1e30f, -1e30f};
#pragma unroll
        for (int ni = 0; ni < 4; ++ni) {
            float4 am = *(const float4*)&Amf[kv0 + ni * 16 + q * 4];
#pragma unroll
            for (int mi = 0; mi < 2; ++mi) {
                st[mi][ni][0] += am.x; st[mi][ni][1] += am.y;
                st[mi][ni][2] += am.z; st[mi][ni][3] += am.w;
#pragma unroll
                for (int r = 0; r < 4; ++r)
                    rmax[mi] = fmaxf(rmax[mi], st[mi][ni][r]);
            }
        }
        float alpha[2], rsum[2];
#pragma unroll
        for (int mi = 0; mi < 2; ++mi) {
            float v = rmax[mi];
            v = fmaxf(v, __shfl_xor(v, 16));
            v = fmaxf(v, __shfl_xor(v, 32));
            float mnew = fmaxf(mst[mi], v);
            alpha[mi] = __expf(mst[mi] - mnew);
            mst[mi] = mnew;
            rsum[mi] = 0.0f;
        }
#pragma unroll
        for (int ni = 0; ni < 4; ++ni)
#pragma unroll
            for (int mi = 0; mi < 2; ++mi) {
                float p0 = __expf(st[mi][ni][0] - mst[mi]);
                float p1 = __expf(st[mi][ni][1] - mst[mi]);
                float p2 = __expf(st[mi][ni][2] - mst[mi]);
                float p3 = __expf(st[mi][ni][3] - mst[mi]);
                rsum[mi] += (p0 + p1) + (p2 + p3);
                uint2 pw = make_uint2(pk2(p0, p1), pk2(p2, p3));
                *(uint2*)&QP[(w * 32 + mi * 16 + lr) * 72 + ni * 16 + q * 4] = pw;
            }
#pragma unroll
        for (int mi = 0; mi < 2; ++mi) {
            float v = rsum[mi];
            v += __shfl_xor(v, 16);
            v += __shfl_xor(v, 32);
            lst[mi] = lst[mi] * alpha[mi] + v;
#pragma unroll
            for (int dj = 0; dj < 4; ++dj) {
                oacc[mi][dj][0] *= alpha[mi]; oacc[mi][dj][1] *= alpha[mi];
                oacc[mi][dj][2] *= alpha[mi]; oacc[mi][dj][3] *= alpha[mi];
            }
        }

        // O^T[d][q] += V^T · P^T   (wave-private P rows; DS in-order)
#pragma unroll
        for (int ks = 0; ks < 2; ++ks) {
            bf16x8 pfB[2];
#pragma unroll
            for (int mi = 0; mi < 2; ++mi)
                pfB[mi] = *(const bf16x8*)&QP[(w * 32 + mi * 16 + lr) * 72 +
                                              ks * 32 + q * 8];
#pragma unroll
            for (int dj = 0; dj < 4; ++dj) {
                bf16x8 vfA = *(const bf16x8*)&Vs[(dj * 16 + lr) * 72 +
                                                 ks * 32 + q * 8];
#pragma unroll
                for (int mi = 0; mi < 2; ++mi)
                    oacc[mi][dj] = __builtin_amdgcn_mfma_f32_16x16x32_bf16(
                        vfA, pfB[mi], oacc[mi][dj], 0, 0, 0);
            }
        }
        __syncthreads();
    }

#pragma unroll
    for (int mi = 0; mi < 2; ++mi) {
        float inv = 1.0f / lst[mi];
        int s = q0 + w * 32 + mi * 16 + lr;
        uint16_t* xp = X + (size_t)(b * SS + s) * HIDN + h * DKK;
#pragma unroll
        for (int dj = 0; dj < 4; ++dj) {
            uint2 pw = make_uint2(pk2(oacc[mi][dj][0] * inv, oacc[mi][dj][1] * inv),
                                  pk2(oacc[mi][dj][2] * inv, oacc[mi][dj][3] * inv));
            *(uint2*)(xp + dj * 16 + q * 4) = pw;
        }
    }
}

extern "C" void kernel_launch(void* const* d_in, const int* in_sizes, int n_in,
                              void* d_out, int out_size, void* d_ws, size_t ws_size,
                              hipStream_t stream) {
    const float* query = (const float*)d_in[0];
    const float* key   = (const float*)d_in[1];
    const float* value = (const float*)d_in[2];
    const float* bias  = (const float*)d_in[3];
    const int*   mask  = (const int*)d_in[4];
    const float* wq = (const float*)d_in[5];
    const float* bq = (const float*)d_in[6];
    const float* wk = (const float*)d_in[7];
    const float* bk = (const float*)d_in[8];
    const float* wv = (const float*)d_in[9];
    const float* bv = (const float*)d_in[10];
    const float* wo = (const float*)d_in[11];
    const float* bo = (const float*)d_in[12];

    const size_t TEN = (size_t)NB * SS * HIDN;       // 4,194,304
    uint16_t* Qin = (uint16_t*)d_ws;
    uint16_t* Kin = Qin + TEN;
    uint16_t* Vin = Kin + TEN;
    uint16_t* W16 = Vin + TEN;                       // 4 x 1M: wq,wk,wv,wo
    uint16_t* Qb  = W16 + 4 * 1048576;
    uint16_t* Kb  = Qb + TEN;
    uint16_t* Vtb = Kb + TEN;
    uint16_t* Xb  = Qin;                             // Qin dead after gemm_qkv

    cvt_all<<<4096, 256, 0, stream>>>(query, key, value, bias,
                                      wq, wk, wv, wo, Qin, Kin, Vin, W16);
    gemm_qkv<<<dim3(8, 32, 3), 256, 0, stream>>>(Qin, Kin, Vin, W16,
                                                 bq, bk, bv, Qb, Kb, Vtb);
    flash_attn<<<dim3(16, 32), 256, 0, stream>>>(Qb, Kb, Vtb, mask, Xb);
    gemm_out<<<dim3(8, 32), 256, 0, stream>>>(Xb, W16 + 3 * 1048576, bo,
                                              (float*)d_out);
}